// Round 1
// 280.679 us; speedup vs baseline: 1.0736x; 1.0736x over previous
//
// R12: score_gemm rewritten as 256^2-tile / BK=64 / 8-wave / 4-phase-per-K-tile
// schedule (raw s_barrier + counted vmcnt once per tile, setprio around MFMA,
// XOR LDS swizzle carried over from R10/R11, chunked XCD swizzle).
// ctx path, preps, reduce unchanged from R11.
#include <hip/hip_runtime.h>

#define NQ 4096
#define NK 8192
#define DIM 1024

typedef __attribute__((ext_vector_type(8))) short short8;
typedef __attribute__((ext_vector_type(4))) float floatx4;
typedef unsigned int u32;
typedef __attribute__((address_space(3))) u32 lds_u32;
typedef __attribute__((address_space(1))) const u32 glb_u32;

__device__ __forceinline__ void gload_lds16(const void* g, void* l) {
    __builtin_amdgcn_global_load_lds((glb_u32*)g, (lds_u32*)l, 16, 0, 0);
}

__device__ __forceinline__ unsigned short f32_bf16(float f) {
    unsigned int u = __float_as_uint(f);
    u += 0x7fff + ((u >> 16) & 1);
    return (unsigned short)(u >> 16);
}

// ---------------------------------------------------------------------------
// Q prep + optional zero(out) + zero(lsum)
// ---------------------------------------------------------------------------
__global__ void prep_q_zero(const float* __restrict__ Q,
                            unsigned short* __restrict__ Qb,
                            float* __restrict__ inv_qn,
                            float* __restrict__ lsum,
                            float* __restrict__ out_zero) {
    int wave = threadIdx.x >> 6;
    int lane = threadIdx.x & 63;
    int row  = blockIdx.x * 4 + wave;
    const float* r = Q + (size_t)row * DIM;
    float s = 0.f;
#pragma unroll
    for (int c = 0; c < 4; ++c) {
        float4 f = *(const float4*)(r + c * 256 + lane * 4);
        s += f.x * f.x + f.y * f.y + f.z * f.z + f.w * f.w;
        ushort4 b;
        b.x = f32_bf16(f.x); b.y = f32_bf16(f.y);
        b.z = f32_bf16(f.z); b.w = f32_bf16(f.w);
        *(ushort4*)(Qb + (size_t)row * DIM + c * 256 + lane * 4) = b;
    }
#pragma unroll
    for (int off = 32; off > 0; off >>= 1) s += __shfl_xor(s, off);
    if (lane == 0) inv_qn[row] = 1.0f / sqrtf(s);

    float4 z = make_float4(0.f, 0.f, 0.f, 0.f);
    if (out_zero) {
#pragma unroll
        for (int c = 0; c < 4; ++c)
            *(float4*)(out_zero + (size_t)blockIdx.x * 4096 + c * 1024 + threadIdx.x * 4) = z;
    }
    if (blockIdx.x < 4)
        *(float4*)(lsum + blockIdx.x * 1024 + threadIdx.x * 4) = z;
}

// ---------------------------------------------------------------------------
// K prep: bf16 convert + 1/norm
// ---------------------------------------------------------------------------
__global__ void prep_norm_cvt(const float* __restrict__ src,
                              unsigned short* __restrict__ dst,
                              float* __restrict__ inv_norm) {
    int wave = threadIdx.x >> 6;
    int lane = threadIdx.x & 63;
    int row  = blockIdx.x * 4 + wave;
    const float* r = src + (size_t)row * DIM;
    float s = 0.f;
#pragma unroll
    for (int c = 0; c < 4; ++c) {
        float4 f = *(const float4*)(r + c * 256 + lane * 4);
        s += f.x * f.x + f.y * f.y + f.z * f.z + f.w * f.w;
        ushort4 b;
        b.x = f32_bf16(f.x); b.y = f32_bf16(f.y);
        b.z = f32_bf16(f.z); b.w = f32_bf16(f.w);
        *(ushort4*)(dst + (size_t)row * DIM + c * 256 + lane * 4) = b;
    }
#pragma unroll
    for (int off = 32; off > 0; off >>= 1) s += __shfl_xor(s, off);
    if (lane == 0) inv_norm[row] = 1.0f / sqrtf(s);
}

// ---------------------------------------------------------------------------
// transpose + convert: Kt[d][kn] = bf16(K[kn][d])
// ---------------------------------------------------------------------------
__global__ void transpose_cvt(const float* __restrict__ K,
                              unsigned short* __restrict__ Kt) {
    __shared__ float t[64][65];
    int kn0 = blockIdx.x * 64, d0 = blockIdx.y * 64;
    int tid = threadIdx.x;
    int r  = tid >> 4;
    int c4 = (tid & 15) * 4;
#pragma unroll
    for (int s = 0; s < 4; ++s) {
        int kk = s * 16 + r;
        float4 f = *(const float4*)(K + (size_t)(kn0 + kk) * DIM + d0 + c4);
        t[kk][c4 + 0] = f.x; t[kk][c4 + 1] = f.y;
        t[kk][c4 + 2] = f.z; t[kk][c4 + 3] = f.w;
    }
    __syncthreads();
#pragma unroll
    for (int s = 0; s < 4; ++s) {
        int dd = s * 16 + r;
        ushort4 b;
        b.x = f32_bf16(t[c4 + 0][dd]);
        b.y = f32_bf16(t[c4 + 1][dd]);
        b.z = f32_bf16(t[c4 + 2][dd]);
        b.w = f32_bf16(t[c4 + 3][dd]);
        *(ushort4*)(Kt + (size_t)(d0 + dd) * NK + kn0 + c4) = b;
    }
}

// ---------------------------------------------------------------------------
// GEMM 1 (R12): 256x256 tile, BK=64 (two 32-k panels), 8 waves (2Mx4N),
// 4 phases per K-tile, raw s_barrier + one counted-vmcnt drain per tile,
// setprio(1) around MFMA clusters, XOR LDS swizzle, chunked XCD swizzle.
// Epilogue: exp + bf16 P store + lsum atomics (same math as R11).
// ---------------------------------------------------------------------------
__global__ __launch_bounds__(512, 2) void score_gemm(
        const unsigned short* __restrict__ Qb,
        const unsigned short* __restrict__ Kb,
        const float* __restrict__ inv_qn,
        const float* __restrict__ inv_kn,
        unsigned short* __restrict__ P,
        float* __restrict__ lsum) {
    // [buf][panel(k 0-31 / 32-63)][256 rows * 32 cols], 128 KiB total
    __shared__ __align__(16) unsigned short A_lds[2][2][256 * 32];
    __shared__ __align__(16) unsigned short B_lds[2][2][256 * 32];

    // chunked XCD swizzle: each XCD owns 4 contiguous n-panels (2 MB K -> L2)
    int bid = blockIdx.x;
    int swz = (bid & 7) * 64 + (bid >> 3);
    int q0  = (swz & 15) * 256;
    int n0  = (swz >> 4) * 256;

    int tid  = threadIdx.x;
    int wave = tid >> 6, lane = tid & 63;
    int wm = wave >> 2, wn = wave & 3;       // 2 x 4 wave grid
    int quad = lane >> 4, l16 = lane & 15;
    int rcol = (quad ^ ((l16 >> 1) & 3)) * 8;   // swizzled read chunk

    // staging: thread covers rows (tid>>2) and (tid>>2)+128 of the 256-row
    // panel; global source pre-swizzled so LDS dest stays linear.
    int schunk = ((tid & 3) ^ ((tid >> 3) & 3)) * 8;
    const unsigned short* gA = Qb + (size_t)(q0 + (tid >> 2)) * DIM + schunk;
    const unsigned short* gB = Kb + (size_t)(n0 + (tid >> 2)) * DIM + schunk;

#define STG_A(t1, pan)                                                \
    do {                                                              \
        const unsigned short* _g = gA + (t1) * 64 + (pan) * 32;       \
        unsigned short* _l = &A_lds[(t1) & 1][pan][wave * 512];       \
        gload_lds16(_g, _l);                                          \
        gload_lds16(_g + (size_t)128 * DIM, _l + 4096);               \
    } while (0)
#define STG_B(t1, pan)                                                \
    do {                                                              \
        const unsigned short* _g = gB + (t1) * 64 + (pan) * 32;       \
        unsigned short* _l = &B_lds[(t1) & 1][pan][wave * 512];       \
        gload_lds16(_g, _l);                                          \
        gload_lds16(_g + (size_t)128 * DIM, _l + 4096);               \
    } while (0)

    floatx4 acc[8][4];
#pragma unroll
    for (int i = 0; i < 8; ++i)
#pragma unroll
        for (int j = 0; j < 4; ++j) acc[i][j] = (floatx4)(0.0f);

    short8 a[4][2], bA[2][2], bB[2][2];

    // prologue: stage tile 0 fully, drain, barrier
    STG_A(0, 0); STG_A(0, 1); STG_B(0, 0); STG_B(0, 1);
    asm volatile("s_waitcnt vmcnt(0)" ::: "memory");
    __syncthreads();

    for (int t = 0; t < 16; ++t) {
        const unsigned short* A0 = &A_lds[t & 1][0][0];
        const unsigned short* A1 = &A_lds[t & 1][1][0];
        const unsigned short* B0 = &B_lds[t & 1][0][0];
        const unsigned short* B1 = &B_lds[t & 1][1][0];
        const int ar = (wm * 128 + l16) * 32 + rcol;   // + mi*512
        const int br = (wn * 64 + l16) * 32 + rcol;    // + nj*512

        // ---- phase A: read A(mi0-3) + B(nj0-1); stage t+1 A panels ----
#pragma unroll
        for (int mi = 0; mi < 4; ++mi) {
            a[mi][0] = *(const short8*)&A0[ar + mi * 512];
            a[mi][1] = *(const short8*)&A1[ar + mi * 512];
        }
#pragma unroll
        for (int nj = 0; nj < 2; ++nj) {
            bA[nj][0] = *(const short8*)&B0[br + nj * 512];
            bA[nj][1] = *(const short8*)&B1[br + nj * 512];
        }
        if (t < 15) { STG_A(t + 1, 0); STG_A(t + 1, 1); }
        __builtin_amdgcn_s_barrier();
        __builtin_amdgcn_s_setprio(1);
#pragma unroll
        for (int mi = 0; mi < 4; ++mi)
#pragma unroll
            for (int nj = 0; nj < 2; ++nj) {
                acc[mi][nj] = __builtin_amdgcn_mfma_f32_16x16x32_bf16(bA[nj][0], a[mi][0], acc[mi][nj], 0, 0, 0);
                acc[mi][nj] = __builtin_amdgcn_mfma_f32_16x16x32_bf16(bA[nj][1], a[mi][1], acc[mi][nj], 0, 0, 0);
            }
        __builtin_amdgcn_s_setprio(0);
        __builtin_amdgcn_s_barrier();

        // ---- phase B: read B(nj2-3); stage t+1 B panels ----
#pragma unroll
        for (int nj = 0; nj < 2; ++nj) {
            bB[nj][0] = *(const short8*)&B0[br + 1024 + nj * 512];
            bB[nj][1] = *(const short8*)&B1[br + 1024 + nj * 512];
        }
        if (t < 15) { STG_B(t + 1, 0); STG_B(t + 1, 1); }
        __builtin_amdgcn_s_barrier();
        __builtin_amdgcn_s_setprio(1);
#pragma unroll
        for (int mi = 0; mi < 4; ++mi)
#pragma unroll
            for (int nj = 0; nj < 2; ++nj) {
                acc[mi][2 + nj] = __builtin_amdgcn_mfma_f32_16x16x32_bf16(bB[nj][0], a[mi][0], acc[mi][2 + nj], 0, 0, 0);
                acc[mi][2 + nj] = __builtin_amdgcn_mfma_f32_16x16x32_bf16(bB[nj][1], a[mi][1], acc[mi][2 + nj], 0, 0, 0);
            }
        __builtin_amdgcn_s_setprio(0);
        __builtin_amdgcn_s_barrier();

        // ---- phase C: read A(mi4-7); reuse bB ----
#pragma unroll
        for (int mi = 0; mi < 4; ++mi) {
            a[mi][0] = *(const short8*)&A0[ar + 2048 + mi * 512];
            a[mi][1] = *(const short8*)&A1[ar + 2048 + mi * 512];
        }
        __builtin_amdgcn_s_barrier();
        __builtin_amdgcn_s_setprio(1);
#pragma unroll
        for (int mi = 0; mi < 4; ++mi)
#pragma unroll
            for (int nj = 0; nj < 2; ++nj) {
                acc[4 + mi][2 + nj] = __builtin_amdgcn_mfma_f32_16x16x32_bf16(bB[nj][0], a[mi][0], acc[4 + mi][2 + nj], 0, 0, 0);
                acc[4 + mi][2 + nj] = __builtin_amdgcn_mfma_f32_16x16x32_bf16(bB[nj][1], a[mi][1], acc[4 + mi][2 + nj], 0, 0, 0);
            }
        __builtin_amdgcn_s_setprio(0);
        __builtin_amdgcn_s_barrier();

        // ---- phase D: pure MFMA (reuse bA); counted drain of t+1 stage ----
        __builtin_amdgcn_s_setprio(1);
#pragma unroll
        for (int mi = 0; mi < 4; ++mi)
#pragma unroll
            for (int nj = 0; nj < 2; ++nj) {
                acc[4 + mi][nj] = __builtin_amdgcn_mfma_f32_16x16x32_bf16(bA[nj][0], a[mi][0], acc[4 + mi][nj], 0, 0, 0);
                acc[4 + mi][nj] = __builtin_amdgcn_mfma_f32_16x16x32_bf16(bA[nj][1], a[mi][1], acc[4 + mi][nj], 0, 0, 0);
            }
        __builtin_amdgcn_s_setprio(0);
        if (t < 15) asm volatile("s_waitcnt vmcnt(0)" ::: "memory");
        __builtin_amdgcn_s_barrier();
    }
#undef STG_A
#undef STG_B

    // epilogue: exp(score * iqn * ikn), bf16 P store, lsum atomics
#pragma unroll
    for (int i = 0; i < 8; ++i) {
        int qrow = q0 + wm * 128 + i * 16 + l16;
        float iqn = inv_qn[qrow];
        float rs = 0.f;
#pragma unroll
        for (int j = 0; j < 4; ++j) {
            int ncol = n0 + wn * 64 + j * 16 + quad * 4;
            float4 ik = *(const float4*)&inv_kn[ncol];
            float p0 = __expf(acc[i][j][0] * iqn * ik.x);
            float p1 = __expf(acc[i][j][1] * iqn * ik.y);
            float p2 = __expf(acc[i][j][2] * iqn * ik.z);
            float p3 = __expf(acc[i][j][3] * iqn * ik.w);
            ushort4 pb;
            pb.x = f32_bf16(p0); pb.y = f32_bf16(p1);
            pb.z = f32_bf16(p2); pb.w = f32_bf16(p3);
            *(ushort4*)&P[(size_t)qrow * NK + ncol] = pb;
            rs += p0 + p1 + p2 + p3;
        }
        rs += __shfl_xor(rs, 16);
        rs += __shfl_xor(rs, 32);
        if (quad == 0) atomicAdd(&lsum[qrow], rs);
    }
}

// ---------------------------------------------------------------------------
// GEMM 2 tier-1: split-K x4 + XCD swizzle, XOR LDS swizzle, OPERAND-SWAPPED,
// plain float4 partial stores into part[z][q][d] (no atomics, no lsum).
// ---------------------------------------------------------------------------
__global__ void ctx_gemm_st(const unsigned short* __restrict__ P,
                            const unsigned short* __restrict__ Kt,
                            float* __restrict__ part) {
    __shared__ __align__(16) unsigned short As[128 * 32];
    __shared__ __align__(16) unsigned short Bs[128 * 32];
    int id = blockIdx.x;
    int r8 = id & 7;
    int t  = id >> 3;
    int x  = t & 7;
    int g  = ((t >> 3) << 3) | r8;   // 0..127
    int y  = g & 31;
    int z  = g >> 5;                 // 0..3
    int q0 = y * 128;
    int d0 = x * 128;
    int kbase = z * (NK / 4);

    int tid = threadIdx.x;
    int wave = tid >> 6, lane = tid & 63;
    int wm = wave >> 1, wn = wave & 1;
    int quad = lane >> 4, l16 = lane & 15;

    int srow   = wave * 32 + (lane >> 2);
    int schunk = (((lane & 3) ^ ((lane >> 3) & 3))) * 8;
    const unsigned short* gA0 = P + (size_t)(q0 + srow) * NK + kbase + schunk;
    const unsigned short* gA1 = gA0 + (size_t)16 * NK;
    const unsigned short* gB0 = Kt + (size_t)(d0 + srow) * NK + kbase + schunk;
    const unsigned short* gB1 = gB0 + (size_t)16 * NK;
    unsigned short* lA0 = As + wave * 32 * 32;
    unsigned short* lA1 = lA0 + 16 * 32;
    unsigned short* lB0 = Bs + wave * 32 * 32;
    unsigned short* lB1 = lB0 + 16 * 32;

    int rcol = (quad ^ ((l16 >> 1) & 3)) * 8;

    floatx4 acc[4][4];
#pragma unroll
    for (int i = 0; i < 4; ++i)
#pragma unroll
        for (int j = 0; j < 4; ++j) acc[i][j] = (floatx4)(0.0f);

    for (int kb = 0; kb < (NK / 4) / 32; ++kb) {
        int k0 = kb * 32;
        __syncthreads();
        gload_lds16(gA0 + k0, lA0);
        gload_lds16(gA1 + k0, lA1);
        gload_lds16(gB0 + k0, lB0);
        gload_lds16(gB1 + k0, lB1);
        __syncthreads();
        short8 a[4], b[4];
#pragma unroll
        for (int i = 0; i < 4; ++i)
            a[i] = *(const short8*)&As[(wm * 64 + i * 16 + l16) * 32 + rcol];
#pragma unroll
        for (int j = 0; j < 4; ++j)
            b[j] = *(const short8*)&Bs[(wn * 64 + j * 16 + l16) * 32 + rcol];
        // swapped: acc[i][j] lane(quad,l16) reg r = C[q=i*16+l16][d=j*16+quad*4+r]
#pragma unroll
        for (int i = 0; i < 4; ++i)
#pragma unroll
            for (int j = 0; j < 4; ++j)
                acc[i][j] = __builtin_amdgcn_mfma_f32_16x16x32_bf16(b[j], a[i], acc[i][j], 0, 0, 0);
    }

    float* pslice = part + (size_t)z * NQ * DIM;
#pragma unroll
    for (int i = 0; i < 4; ++i) {
        int qrow = q0 + wm * 64 + i * 16 + l16;
#pragma unroll
        for (int j = 0; j < 4; ++j) {
            int dcol = d0 + wn * 64 + j * 16 + quad * 4;
            float4 v;
            v.x = acc[i][j][0]; v.y = acc[i][j][1];
            v.z = acc[i][j][2]; v.w = acc[i][j][3];
            *(float4*)&pslice[(size_t)qrow * DIM + dcol] = v;
        }
    }
}

// ---------------------------------------------------------------------------
// reduce: out[q][d] = (sum_z part[z][q][d]) / lsum[q]
// ---------------------------------------------------------------------------
__global__ void reduce_out(const float* __restrict__ part,
                           const float* __restrict__ lsum,
                           float* __restrict__ out) {
    size_t idx = ((size_t)blockIdx.x * 256 + threadIdx.x) * 4;
    int q = (int)(idx >> 10);
    float inv = 1.0f / lsum[q];
    const size_t S = (size_t)NQ * DIM;
    float4 s0 = *(const float4*)(part + idx);
    float4 s1 = *(const float4*)(part + S + idx);
    float4 s2 = *(const float4*)(part + 2 * S + idx);
    float4 s3 = *(const float4*)(part + 3 * S + idx);
    float4 o;
    o.x = (s0.x + s1.x + s2.x + s3.x) * inv;
    o.y = (s0.y + s1.y + s2.y + s3.y) * inv;
    o.z = (s0.z + s1.z + s2.z + s3.z) * inv;
    o.w = (s0.w + s1.w + s2.w + s3.w) * inv;
    *(float4*)(out + idx) = o;
}

// ---------------------------------------------------------------------------
// GEMM 2 tier-2 (exact R10): atomics into pre-zeroed out.
// ---------------------------------------------------------------------------
__global__ void ctx_gemm(const unsigned short* __restrict__ P,
                         const unsigned short* __restrict__ Kt,
                         const float* __restrict__ lsum,
                         float* __restrict__ out) {
    __shared__ __align__(16) unsigned short As[128 * 32];
    __shared__ __align__(16) unsigned short Bs[128 * 32];
    int id = blockIdx.x;
    int r8 = id & 7;
    int t  = id >> 3;
    int x  = t & 7;
    int g  = ((t >> 3) << 3) | r8;
    int y  = g & 31;
    int z  = g >> 5;
    int q0 = y * 128;
    int d0 = x * 128;
    int kbase = z * (NK / 4);

    int tid = threadIdx.x;
    int wave = tid >> 6, lane = tid & 63;
    int wm = wave >> 1, wn = wave & 1;
    int quad = lane >> 4, l16 = lane & 15;

    int srow   = wave * 32 + (lane >> 2);
    int schunk = (((lane & 3) ^ ((lane >> 3) & 3))) * 8;
    const unsigned short* gA0 = P + (size_t)(q0 + srow) * NK + kbase + schunk;
    const unsigned short* gA1 = gA0 + (size_t)16 * NK;
    const unsigned short* gB0 = Kt + (size_t)(d0 + srow) * NK + kbase + schunk;
    const unsigned short* gB1 = gB0 + (size_t)16 * NK;
    unsigned short* lA0 = As + wave * 32 * 32;
    unsigned short* lA1 = lA0 + 16 * 32;
    unsigned short* lB0 = Bs + wave * 32 * 32;
    unsigned short* lB1 = lB0 + 16 * 32;

    int rcol = (quad ^ ((l16 >> 1) & 3)) * 8;

    floatx4 acc[4][4];
#pragma unroll
    for (int i = 0; i < 4; ++i)
#pragma unroll
        for (int j = 0; j < 4; ++j) acc[i][j] = (floatx4)(0.0f);

    for (int kb = 0; kb < (NK / 4) / 32; ++kb) {
        int k0 = kb * 32;
        __syncthreads();
        gload_lds16(gA0 + k0, lA0);
        gload_lds16(gA1 + k0, lA1);
        gload_lds16(gB0 + k0, lB0);
        gload_lds16(gB1 + k0, lB1);
        __syncthreads();
        short8 a[4], b[4];
#pragma unroll
        for (int i = 0; i < 4; ++i)
            a[i] = *(const short8*)&As[(wm * 64 + i * 16 + l16) * 32 + rcol];
#pragma unroll
        for (int j = 0; j < 4; ++j)
            b[j] = *(const short8*)&Bs[(wn * 64 + j * 16 + l16) * 32 + rcol];
#pragma unroll
        for (int i = 0; i < 4; ++i)
#pragma unroll
            for (int j = 0; j < 4; ++j)
                acc[i][j] = __builtin_amdgcn_mfma_f32_16x16x32_bf16(a[i], b[j], acc[i][j], 0, 0, 0);
    }

#pragma unroll
    for (int i = 0; i < 4; ++i) {
        float invl[4];
#pragma unroll
        for (int r = 0; r < 4; ++r)
            invl[r] = 1.0f / lsum[q0 + wm * 64 + i * 16 + quad * 4 + r];
#pragma unroll
        for (int j = 0; j < 4; ++j) {
#pragma unroll
            for (int r = 0; r < 4; ++r) {
                int qrow = q0 + wm * 64 + i * 16 + quad * 4 + r;
                int dcol = d0 + wn * 64 + j * 16 + l16;
                atomicAdd(&out[(size_t)qrow * DIM + dcol], acc[i][j][r] * invl[r]);
            }
        }
    }
}

// ---------------------------------------------------------------------------
// Path D fallback (ws too small) — correct but slow.
// ---------------------------------------------------------------------------
__global__ void fused_fallback(const float* __restrict__ Q,
                               const float* __restrict__ K,
                               float* __restrict__ out) {
    int wave = threadIdx.x >> 6, lane = threadIdx.x & 63;
    int q0 = blockIdx.x * 16 + wave * 4;
    float qv[4][16], acc[4][16], iqn[4], ls[4];
#pragma unroll
    for (int r = 0; r < 4; ++r) {
        float s = 0.f;
#pragma unroll
        for (int c = 0; c < 4; ++c) {
            float4 f = *(const float4*)(Q + (size_t)(q0 + r) * DIM + c * 256 + lane * 4);
            qv[r][c * 4 + 0] = f.x; qv[r][c * 4 + 1] = f.y;
            qv[r][c * 4 + 2] = f.z; qv[r][c * 4 + 3] = f.w;
            s += f.x * f.x + f.y * f.y + f.z * f.z + f.w * f.w;
        }
#pragma unroll
        for (int off = 32; off > 0; off >>= 1) s += __shfl_xor(s, off);
        iqn[r] = 1.0f / sqrtf(s);
        ls[r] = 0.f;
#pragma unroll
        for (int t = 0; t < 16; ++t) acc[r][t] = 0.f;
    }
    for (int k = 0; k < NK; ++k) {
        const float* kr = K + (size_t)k * DIM;
        float kv[16], ss = 0.f;
#pragma unroll
        for (int c = 0; c < 4; ++c) {
            float4 f = *(const float4*)(kr + c * 256 + lane * 4);
            kv[c * 4 + 0] = f.x; kv[c * 4 + 1] = f.y;
            kv[c * 4 + 2] = f.z; kv[c * 4 + 3] = f.w;
            ss += f.x * f.x + f.y * f.y + f.z * f.z + f.w * f.w;
        }
        float d0 = 0.f, d1 = 0.f, d2 = 0.f, d3 = 0.f;
#pragma unroll
        for (int t = 0; t < 16; ++t) {
            d0 += qv[0][t] * kv[t]; d1 += qv[1][t] * kv[t];
            d2 += qv[2][t] * kv[t]; d3 += qv[3][t] * kv[t];
        }
#pragma unroll
        for (int off = 32; off > 0; off >>= 1) {
            ss += __shfl_xor(ss, off);
            d0 += __shfl_xor(d0, off); d1 += __shfl_xor(d1, off);
            d2 += __shfl_xor(d2, off); d3 += __shfl_xor(d3, off);
        }
        float ikn = 1.0f / sqrtf(ss);
        float p0 = __expf(d0 * iqn[0] * ikn), p1 = __expf(d1 * iqn[1] * ikn);
        float p2 = __expf(d2 * iqn[2] * ikn), p3 = __expf(d3 * iqn[3] * ikn);
        ls[0] += p0; ls[1] += p1; ls[2] += p2; ls[3] += p3;
#pragma unroll
        for (int t = 0; t < 16; ++t) {
            acc[0][t] += p0 * kv[t]; acc[1][t] += p1 * kv[t];
            acc[2][t] += p2 * kv[t]; acc[3][t] += p3 * kv[t];
        }
    }
#pragma unroll
    for (int r = 0; r < 4; ++r) {
        float inv = 1.0f / ls[r];
#pragma unroll
        for (int c = 0; c < 4; ++c) {
            float4 o;
            o.x = acc[r][c * 4 + 0] * inv; o.y = acc[r][c * 4 + 1] * inv;
            o.z = acc[r][c * 4 + 2] * inv; o.w = acc[r][c * 4 + 3] * inv;
            *(float4*)(out + (size_t)(q0 + r) * DIM + c * 256 + lane * 4) = o;
        }
    }
}

// ---------------------------------------------------------------------------
// launch — tiers:
//  T1 (ws>=152M+64K): Kt[0,16M) overlap Qb/Kb, P[24,88M), part[88,152M),
//                     scalars @152M; ctx_gemm_st + reduce_out.
//  T2 (ws>=88M+64K):  exact R10 (atomics).
//  else: fallback.
// ---------------------------------------------------------------------------
extern "C" void kernel_launch(void* const* d_in, const int* in_sizes, int n_in,
                              void* d_out, int out_size, void* d_ws, size_t ws_size,
                              hipStream_t stream) {
    const float* Q = (const float*)d_in[0];
    const float* K = (const float*)d_in[1];
    float* out = (float*)d_out;
    char* ws = (char*)d_ws;

    const size_t REQ_T1 = ((size_t)152u << 20) + 65536;
    const size_t REQ_T2 = ((size_t)88u << 20) + 65536;

    if (ws_size >= REQ_T1) {
        unsigned short* Kt = (unsigned short*)(ws);
        unsigned short* Qb = (unsigned short*)(ws);
        unsigned short* Kb = (unsigned short*)(ws + (size_t)(8u << 20));
        unsigned short* P  = (unsigned short*)(ws + (size_t)(24u << 20));
        float* part   = (float*)(ws + (size_t)(88u << 20));
        float* inv_qn = (float*)(ws + (size_t)(152u << 20));
        float* inv_kn = (float*)(ws + (size_t)(152u << 20) + 16384);
        float* lsum   = (float*)(ws + (size_t)(152u << 20) + 49152);

        prep_q_zero<<<NQ / 4, 256, 0, stream>>>(Q, Qb, inv_qn, lsum, nullptr);
        prep_norm_cvt<<<NK / 4, 256, 0, stream>>>(K, Kb, inv_kn);
        score_gemm<<<512, 512, 0, stream>>>(Qb, Kb, inv_qn, inv_kn, P, lsum);
        transpose_cvt<<<dim3(NK / 64, DIM / 64), 256, 0, stream>>>(K, Kt);
        ctx_gemm_st<<<1024, 256, 0, stream>>>(P, Kt, part);
        reduce_out<<<NQ * DIM / 1024, 256, 0, stream>>>(part, lsum, out);
    } else if (ws_size >= REQ_T2) {
        unsigned short* Kt = (unsigned short*)(ws);
        unsigned short* Qb = (unsigned short*)(ws);
        unsigned short* Kb = (unsigned short*)(ws + (size_t)(8u << 20));
        unsigned short* P  = (unsigned short*)(ws + (size_t)(24u << 20));
        float* inv_qn = (float*)(ws + (size_t)(88u << 20));
        float* inv_kn = (float*)(ws + (size_t)(88u << 20) + 16384);
        float* lsum   = (float*)(ws + (size_t)(88u << 20) + 49152);

        prep_q_zero<<<NQ / 4, 256, 0, stream>>>(Q, Qb, inv_qn, lsum, out);
        prep_norm_cvt<<<NK / 4, 256, 0, stream>>>(K, Kb, inv_kn);
        score_gemm<<<512, 512, 0, stream>>>(Qb, Kb, inv_qn, inv_kn, P, lsum);
        transpose_cvt<<<dim3(NK / 64, DIM / 64), 256, 0, stream>>>(K, Kt);
        ctx_gemm<<<1024, 256, 0, stream>>>(P, Kt, lsum, out);
    } else {
        fused_fallback<<<NQ / 16, 256, 0, stream>>>(Q, K, out);
    }
}

// Round 2
// 261.280 us; speedup vs baseline: 1.1533x; 1.0742x over previous
//
// R13: ctx_gemm_st ported to the 256^2-tile / BK=64 / 8-wave / 4-phase
// schedule proven in R12's score_gemm (raw s_barrier + counted vmcnt once
// per K-tile, setprio around MFMA, XOR LDS swizzle, chunked XCD swizzle,
// split-K z=4 -> grid 256). score_gemm/preps/reduce/tier-2 unchanged.
#include <hip/hip_runtime.h>

#define NQ 4096
#define NK 8192
#define DIM 1024

typedef __attribute__((ext_vector_type(8))) short short8;
typedef __attribute__((ext_vector_type(4))) float floatx4;
typedef unsigned int u32;
typedef __attribute__((address_space(3))) u32 lds_u32;
typedef __attribute__((address_space(1))) const u32 glb_u32;

__device__ __forceinline__ void gload_lds16(const void* g, void* l) {
    __builtin_amdgcn_global_load_lds((glb_u32*)g, (lds_u32*)l, 16, 0, 0);
}

__device__ __forceinline__ unsigned short f32_bf16(float f) {
    unsigned int u = __float_as_uint(f);
    u += 0x7fff + ((u >> 16) & 1);
    return (unsigned short)(u >> 16);
}

// ---------------------------------------------------------------------------
// Q prep + optional zero(out) + zero(lsum)
// ---------------------------------------------------------------------------
__global__ void prep_q_zero(const float* __restrict__ Q,
                            unsigned short* __restrict__ Qb,
                            float* __restrict__ inv_qn,
                            float* __restrict__ lsum,
                            float* __restrict__ out_zero) {
    int wave = threadIdx.x >> 6;
    int lane = threadIdx.x & 63;
    int row  = blockIdx.x * 4 + wave;
    const float* r = Q + (size_t)row * DIM;
    float s = 0.f;
#pragma unroll
    for (int c = 0; c < 4; ++c) {
        float4 f = *(const float4*)(r + c * 256 + lane * 4);
        s += f.x * f.x + f.y * f.y + f.z * f.z + f.w * f.w;
        ushort4 b;
        b.x = f32_bf16(f.x); b.y = f32_bf16(f.y);
        b.z = f32_bf16(f.z); b.w = f32_bf16(f.w);
        *(ushort4*)(Qb + (size_t)row * DIM + c * 256 + lane * 4) = b;
    }
#pragma unroll
    for (int off = 32; off > 0; off >>= 1) s += __shfl_xor(s, off);
    if (lane == 0) inv_qn[row] = 1.0f / sqrtf(s);

    float4 z = make_float4(0.f, 0.f, 0.f, 0.f);
    if (out_zero) {
#pragma unroll
        for (int c = 0; c < 4; ++c)
            *(float4*)(out_zero + (size_t)blockIdx.x * 4096 + c * 1024 + threadIdx.x * 4) = z;
    }
    if (blockIdx.x < 4)
        *(float4*)(lsum + blockIdx.x * 1024 + threadIdx.x * 4) = z;
}

// ---------------------------------------------------------------------------
// K prep: bf16 convert + 1/norm
// ---------------------------------------------------------------------------
__global__ void prep_norm_cvt(const float* __restrict__ src,
                              unsigned short* __restrict__ dst,
                              float* __restrict__ inv_norm) {
    int wave = threadIdx.x >> 6;
    int lane = threadIdx.x & 63;
    int row  = blockIdx.x * 4 + wave;
    const float* r = src + (size_t)row * DIM;
    float s = 0.f;
#pragma unroll
    for (int c = 0; c < 4; ++c) {
        float4 f = *(const float4*)(r + c * 256 + lane * 4);
        s += f.x * f.x + f.y * f.y + f.z * f.z + f.w * f.w;
        ushort4 b;
        b.x = f32_bf16(f.x); b.y = f32_bf16(f.y);
        b.z = f32_bf16(f.z); b.w = f32_bf16(f.w);
        *(ushort4*)(dst + (size_t)row * DIM + c * 256 + lane * 4) = b;
    }
#pragma unroll
    for (int off = 32; off > 0; off >>= 1) s += __shfl_xor(s, off);
    if (lane == 0) inv_norm[row] = 1.0f / sqrtf(s);
}

// ---------------------------------------------------------------------------
// transpose + convert: Kt[d][kn] = bf16(K[kn][d])
// ---------------------------------------------------------------------------
__global__ void transpose_cvt(const float* __restrict__ K,
                              unsigned short* __restrict__ Kt) {
    __shared__ float t[64][65];
    int kn0 = blockIdx.x * 64, d0 = blockIdx.y * 64;
    int tid = threadIdx.x;
    int r  = tid >> 4;
    int c4 = (tid & 15) * 4;
#pragma unroll
    for (int s = 0; s < 4; ++s) {
        int kk = s * 16 + r;
        float4 f = *(const float4*)(K + (size_t)(kn0 + kk) * DIM + d0 + c4);
        t[kk][c4 + 0] = f.x; t[kk][c4 + 1] = f.y;
        t[kk][c4 + 2] = f.z; t[kk][c4 + 3] = f.w;
    }
    __syncthreads();
#pragma unroll
    for (int s = 0; s < 4; ++s) {
        int dd = s * 16 + r;
        ushort4 b;
        b.x = f32_bf16(t[c4 + 0][dd]);
        b.y = f32_bf16(t[c4 + 1][dd]);
        b.z = f32_bf16(t[c4 + 2][dd]);
        b.w = f32_bf16(t[c4 + 3][dd]);
        *(ushort4*)(Kt + (size_t)(d0 + dd) * NK + kn0 + c4) = b;
    }
}

// ---------------------------------------------------------------------------
// GEMM 1 (R12): 256x256 tile, BK=64 (two 32-k panels), 8 waves (2Mx4N),
// 4 phases per K-tile, raw s_barrier + one counted-vmcnt drain per tile,
// setprio(1) around MFMA clusters, XOR LDS swizzle, chunked XCD swizzle.
// Epilogue: exp + bf16 P store + lsum atomics.
// ---------------------------------------------------------------------------
__global__ __launch_bounds__(512, 2) void score_gemm(
        const unsigned short* __restrict__ Qb,
        const unsigned short* __restrict__ Kb,
        const float* __restrict__ inv_qn,
        const float* __restrict__ inv_kn,
        unsigned short* __restrict__ P,
        float* __restrict__ lsum) {
    // [buf][panel(k 0-31 / 32-63)][256 rows * 32 cols], 128 KiB total
    __shared__ __align__(16) unsigned short A_lds[2][2][256 * 32];
    __shared__ __align__(16) unsigned short B_lds[2][2][256 * 32];

    // chunked XCD swizzle: each XCD owns 4 contiguous n-panels (2 MB K -> L2)
    int bid = blockIdx.x;
    int swz = (bid & 7) * 64 + (bid >> 3);
    int q0  = (swz & 15) * 256;
    int n0  = (swz >> 4) * 256;

    int tid  = threadIdx.x;
    int wave = tid >> 6, lane = tid & 63;
    int wm = wave >> 2, wn = wave & 3;       // 2 x 4 wave grid
    int quad = lane >> 4, l16 = lane & 15;
    int rcol = (quad ^ ((l16 >> 1) & 3)) * 8;   // swizzled read chunk

    // staging: thread covers rows (tid>>2) and (tid>>2)+128 of the 256-row
    // panel; global source pre-swizzled so LDS dest stays linear.
    int schunk = ((tid & 3) ^ ((tid >> 3) & 3)) * 8;
    const unsigned short* gA = Qb + (size_t)(q0 + (tid >> 2)) * DIM + schunk;
    const unsigned short* gB = Kb + (size_t)(n0 + (tid >> 2)) * DIM + schunk;

#define STG_A(t1, pan)                                                \
    do {                                                              \
        const unsigned short* _g = gA + (t1) * 64 + (pan) * 32;       \
        unsigned short* _l = &A_lds[(t1) & 1][pan][wave * 512];       \
        gload_lds16(_g, _l);                                          \
        gload_lds16(_g + (size_t)128 * DIM, _l + 4096);               \
    } while (0)
#define STG_B(t1, pan)                                                \
    do {                                                              \
        const unsigned short* _g = gB + (t1) * 64 + (pan) * 32;       \
        unsigned short* _l = &B_lds[(t1) & 1][pan][wave * 512];       \
        gload_lds16(_g, _l);                                          \
        gload_lds16(_g + (size_t)128 * DIM, _l + 4096);               \
    } while (0)

    floatx4 acc[8][4];
#pragma unroll
    for (int i = 0; i < 8; ++i)
#pragma unroll
        for (int j = 0; j < 4; ++j) acc[i][j] = (floatx4)(0.0f);

    short8 a[4][2], bA[2][2], bB[2][2];

    // prologue: stage tile 0 fully, drain, barrier
    STG_A(0, 0); STG_A(0, 1); STG_B(0, 0); STG_B(0, 1);
    asm volatile("s_waitcnt vmcnt(0)" ::: "memory");
    __syncthreads();

    for (int t = 0; t < 16; ++t) {
        const unsigned short* A0 = &A_lds[t & 1][0][0];
        const unsigned short* A1 = &A_lds[t & 1][1][0];
        const unsigned short* B0 = &B_lds[t & 1][0][0];
        const unsigned short* B1 = &B_lds[t & 1][1][0];
        const int ar = (wm * 128 + l16) * 32 + rcol;   // + mi*512
        const int br = (wn * 64 + l16) * 32 + rcol;    // + nj*512

        // ---- phase A: read A(mi0-3) + B(nj0-1); stage t+1 A panels ----
#pragma unroll
        for (int mi = 0; mi < 4; ++mi) {
            a[mi][0] = *(const short8*)&A0[ar + mi * 512];
            a[mi][1] = *(const short8*)&A1[ar + mi * 512];
        }
#pragma unroll
        for (int nj = 0; nj < 2; ++nj) {
            bA[nj][0] = *(const short8*)&B0[br + nj * 512];
            bA[nj][1] = *(const short8*)&B1[br + nj * 512];
        }
        if (t < 15) { STG_A(t + 1, 0); STG_A(t + 1, 1); }
        __builtin_amdgcn_s_barrier();
        __builtin_amdgcn_s_setprio(1);
#pragma unroll
        for (int mi = 0; mi < 4; ++mi)
#pragma unroll
            for (int nj = 0; nj < 2; ++nj) {
                acc[mi][nj] = __builtin_amdgcn_mfma_f32_16x16x32_bf16(bA[nj][0], a[mi][0], acc[mi][nj], 0, 0, 0);
                acc[mi][nj] = __builtin_amdgcn_mfma_f32_16x16x32_bf16(bA[nj][1], a[mi][1], acc[mi][nj], 0, 0, 0);
            }
        __builtin_amdgcn_s_setprio(0);
        __builtin_amdgcn_s_barrier();

        // ---- phase B: read B(nj2-3); stage t+1 B panels ----
#pragma unroll
        for (int nj = 0; nj < 2; ++nj) {
            bB[nj][0] = *(const short8*)&B0[br + 1024 + nj * 512];
            bB[nj][1] = *(const short8*)&B1[br + 1024 + nj * 512];
        }
        if (t < 15) { STG_B(t + 1, 0); STG_B(t + 1, 1); }
        __builtin_amdgcn_s_barrier();
        __builtin_amdgcn_s_setprio(1);
#pragma unroll
        for (int mi = 0; mi < 4; ++mi)
#pragma unroll
            for (int nj = 0; nj < 2; ++nj) {
                acc[mi][2 + nj] = __builtin_amdgcn_mfma_f32_16x16x32_bf16(bB[nj][0], a[mi][0], acc[mi][2 + nj], 0, 0, 0);
                acc[mi][2 + nj] = __builtin_amdgcn_mfma_f32_16x16x32_bf16(bB[nj][1], a[mi][1], acc[mi][2 + nj], 0, 0, 0);
            }
        __builtin_amdgcn_s_setprio(0);
        __builtin_amdgcn_s_barrier();

        // ---- phase C: read A(mi4-7); reuse bB ----
#pragma unroll
        for (int mi = 0; mi < 4; ++mi) {
            a[mi][0] = *(const short8*)&A0[ar + 2048 + mi * 512];
            a[mi][1] = *(const short8*)&A1[ar + 2048 + mi * 512];
        }
        __builtin_amdgcn_s_barrier();
        __builtin_amdgcn_s_setprio(1);
#pragma unroll
        for (int mi = 0; mi < 4; ++mi)
#pragma unroll
            for (int nj = 0; nj < 2; ++nj) {
                acc[4 + mi][2 + nj] = __builtin_amdgcn_mfma_f32_16x16x32_bf16(bB[nj][0], a[mi][0], acc[4 + mi][2 + nj], 0, 0, 0);
                acc[4 + mi][2 + nj] = __builtin_amdgcn_mfma_f32_16x16x32_bf16(bB[nj][1], a[mi][1], acc[4 + mi][2 + nj], 0, 0, 0);
            }
        __builtin_amdgcn_s_setprio(0);
        __builtin_amdgcn_s_barrier();

        // ---- phase D: pure MFMA (reuse bA); counted drain of t+1 stage ----
        __builtin_amdgcn_s_setprio(1);
#pragma unroll
        for (int mi = 0; mi < 4; ++mi)
#pragma unroll
            for (int nj = 0; nj < 2; ++nj) {
                acc[4 + mi][nj] = __builtin_amdgcn_mfma_f32_16x16x32_bf16(bA[nj][0], a[mi][0], acc[4 + mi][nj], 0, 0, 0);
                acc[4 + mi][nj] = __builtin_amdgcn_mfma_f32_16x16x32_bf16(bA[nj][1], a[mi][1], acc[4 + mi][nj], 0, 0, 0);
            }
        __builtin_amdgcn_s_setprio(0);
        if (t < 15) asm volatile("s_waitcnt vmcnt(0)" ::: "memory");
        __builtin_amdgcn_s_barrier();
    }
#undef STG_A
#undef STG_B

    // epilogue: exp(score * iqn * ikn), bf16 P store, lsum atomics
#pragma unroll
    for (int i = 0; i < 8; ++i) {
        int qrow = q0 + wm * 128 + i * 16 + l16;
        float iqn = inv_qn[qrow];
        float rs = 0.f;
#pragma unroll
        for (int j = 0; j < 4; ++j) {
            int ncol = n0 + wn * 64 + j * 16 + quad * 4;
            float4 ik = *(const float4*)&inv_kn[ncol];
            float p0 = __expf(acc[i][j][0] * iqn * ik.x);
            float p1 = __expf(acc[i][j][1] * iqn * ik.y);
            float p2 = __expf(acc[i][j][2] * iqn * ik.z);
            float p3 = __expf(acc[i][j][3] * iqn * ik.w);
            ushort4 pb;
            pb.x = f32_bf16(p0); pb.y = f32_bf16(p1);
            pb.z = f32_bf16(p2); pb.w = f32_bf16(p3);
            *(ushort4*)&P[(size_t)qrow * NK + ncol] = pb;
            rs += p0 + p1 + p2 + p3;
        }
        rs += __shfl_xor(rs, 16);
        rs += __shfl_xor(rs, 32);
        if (quad == 0) atomicAdd(&lsum[qrow], rs);
    }
}

// ---------------------------------------------------------------------------
// GEMM 2 tier-1 (R13): 256x256 tile, BK=64, 8 waves, 4-phase schedule,
// split-K z=4 (grid 256 = 1 block/CU), chunked XCD swizzle, XOR LDS swizzle,
// OPERAND-SWAPPED MFMA, plain float4 partial stores into part[z][q][d].
// ---------------------------------------------------------------------------
__global__ __launch_bounds__(512, 2) void ctx_gemm_st(
        const unsigned short* __restrict__ P,
        const unsigned short* __restrict__ Kt,
        float* __restrict__ part) {
    __shared__ __align__(16) unsigned short A_lds[2][2][256 * 32];
    __shared__ __align__(16) unsigned short B_lds[2][2][256 * 32];

    // grid 256: logical id = z*64 + y*4 + x (z=K-split, y=q-tile, x=d-tile).
    // chunked XCD swizzle: XCD c owns logical [c*32,(c+1)*32) = half a
    // z-slice -> its 4 Kt d-panels (4 MB) stay L2-resident.
    int bid = blockIdx.x;
    int swz = (bid & 7) * 32 + (bid >> 3);
    int z  = swz >> 6;
    int y  = (swz >> 2) & 15;
    int x  = swz & 3;
    int q0 = y * 256;
    int d0 = x * 256;
    int kbase = z * (NK / 4);

    int tid  = threadIdx.x;
    int wave = tid >> 6, lane = tid & 63;
    int wm = wave >> 2, wn = wave & 3;       // 2 x 4 wave grid
    int quad = lane >> 4, l16 = lane & 15;
    int rcol = (quad ^ ((l16 >> 1) & 3)) * 8;

    int schunk = ((tid & 3) ^ ((tid >> 3) & 3)) * 8;
    const unsigned short* gA = P  + (size_t)(q0 + (tid >> 2)) * NK + kbase + schunk;
    const unsigned short* gB = Kt + (size_t)(d0 + (tid >> 2)) * NK + kbase + schunk;

#define STG_A(t1, pan)                                                \
    do {                                                              \
        const unsigned short* _g = gA + (t1) * 64 + (pan) * 32;       \
        unsigned short* _l = &A_lds[(t1) & 1][pan][wave * 512];       \
        gload_lds16(_g, _l);                                          \
        gload_lds16(_g + (size_t)128 * NK, _l + 4096);                \
    } while (0)
#define STG_B(t1, pan)                                                \
    do {                                                              \
        const unsigned short* _g = gB + (t1) * 64 + (pan) * 32;       \
        unsigned short* _l = &B_lds[(t1) & 1][pan][wave * 512];       \
        gload_lds16(_g, _l);                                          \
        gload_lds16(_g + (size_t)128 * NK, _l + 4096);                \
    } while (0)

    floatx4 acc[8][4];
#pragma unroll
    for (int i = 0; i < 8; ++i)
#pragma unroll
        for (int j = 0; j < 4; ++j) acc[i][j] = (floatx4)(0.0f);

    short8 a[4][2], bA[2][2], bB[2][2];

    STG_A(0, 0); STG_A(0, 1); STG_B(0, 0); STG_B(0, 1);
    asm volatile("s_waitcnt vmcnt(0)" ::: "memory");
    __syncthreads();

    const int NT = (NK / 4) / 64;   // 32 K-tiles
    for (int t = 0; t < NT; ++t) {
        const unsigned short* A0 = &A_lds[t & 1][0][0];
        const unsigned short* A1 = &A_lds[t & 1][1][0];
        const unsigned short* B0 = &B_lds[t & 1][0][0];
        const unsigned short* B1 = &B_lds[t & 1][1][0];
        const int ar = (wm * 128 + l16) * 32 + rcol;
        const int br = (wn * 64 + l16) * 32 + rcol;

        // ---- phase A ----
#pragma unroll
        for (int mi = 0; mi < 4; ++mi) {
            a[mi][0] = *(const short8*)&A0[ar + mi * 512];
            a[mi][1] = *(const short8*)&A1[ar + mi * 512];
        }
#pragma unroll
        for (int nj = 0; nj < 2; ++nj) {
            bA[nj][0] = *(const short8*)&B0[br + nj * 512];
            bA[nj][1] = *(const short8*)&B1[br + nj * 512];
        }
        if (t < NT - 1) { STG_A(t + 1, 0); STG_A(t + 1, 1); }
        __builtin_amdgcn_s_barrier();
        __builtin_amdgcn_s_setprio(1);
#pragma unroll
        for (int mi = 0; mi < 4; ++mi)
#pragma unroll
            for (int nj = 0; nj < 2; ++nj) {
                acc[mi][nj] = __builtin_amdgcn_mfma_f32_16x16x32_bf16(bA[nj][0], a[mi][0], acc[mi][nj], 0, 0, 0);
                acc[mi][nj] = __builtin_amdgcn_mfma_f32_16x16x32_bf16(bA[nj][1], a[mi][1], acc[mi][nj], 0, 0, 0);
            }
        __builtin_amdgcn_s_setprio(0);
        __builtin_amdgcn_s_barrier();

        // ---- phase B ----
#pragma unroll
        for (int nj = 0; nj < 2; ++nj) {
            bB[nj][0] = *(const short8*)&B0[br + 1024 + nj * 512];
            bB[nj][1] = *(const short8*)&B1[br + 1024 + nj * 512];
        }
        if (t < NT - 1) { STG_B(t + 1, 0); STG_B(t + 1, 1); }
        __builtin_amdgcn_s_barrier();
        __builtin_amdgcn_s_setprio(1);
#pragma unroll
        for (int mi = 0; mi < 4; ++mi)
#pragma unroll
            for (int nj = 0; nj < 2; ++nj) {
                acc[mi][2 + nj] = __builtin_amdgcn_mfma_f32_16x16x32_bf16(bB[nj][0], a[mi][0], acc[mi][2 + nj], 0, 0, 0);
                acc[mi][2 + nj] = __builtin_amdgcn_mfma_f32_16x16x32_bf16(bB[nj][1], a[mi][1], acc[mi][2 + nj], 0, 0, 0);
            }
        __builtin_amdgcn_s_setprio(0);
        __builtin_amdgcn_s_barrier();

        // ---- phase C ----
#pragma unroll
        for (int mi = 0; mi < 4; ++mi) {
            a[mi][0] = *(const short8*)&A0[ar + 2048 + mi * 512];
            a[mi][1] = *(const short8*)&A1[ar + 2048 + mi * 512];
        }
        __builtin_amdgcn_s_barrier();
        __builtin_amdgcn_s_setprio(1);
#pragma unroll
        for (int mi = 0; mi < 4; ++mi)
#pragma unroll
            for (int nj = 0; nj < 2; ++nj) {
                acc[4 + mi][2 + nj] = __builtin_amdgcn_mfma_f32_16x16x32_bf16(bB[nj][0], a[mi][0], acc[4 + mi][2 + nj], 0, 0, 0);
                acc[4 + mi][2 + nj] = __builtin_amdgcn_mfma_f32_16x16x32_bf16(bB[nj][1], a[mi][1], acc[4 + mi][2 + nj], 0, 0, 0);
            }
        __builtin_amdgcn_s_setprio(0);
        __builtin_amdgcn_s_barrier();

        // ---- phase D ----
        __builtin_amdgcn_s_setprio(1);
#pragma unroll
        for (int mi = 0; mi < 4; ++mi)
#pragma unroll
            for (int nj = 0; nj < 2; ++nj) {
                acc[4 + mi][nj] = __builtin_amdgcn_mfma_f32_16x16x32_bf16(bA[nj][0], a[mi][0], acc[4 + mi][nj], 0, 0, 0);
                acc[4 + mi][nj] = __builtin_amdgcn_mfma_f32_16x16x32_bf16(bA[nj][1], a[mi][1], acc[4 + mi][nj], 0, 0, 0);
            }
        __builtin_amdgcn_s_setprio(0);
        if (t < NT - 1) asm volatile("s_waitcnt vmcnt(0)" ::: "memory");
        __builtin_amdgcn_s_barrier();
    }
#undef STG_A
#undef STG_B

    // epilogue: swapped layout -> acc[i][j] lane(quad,l16) reg r =
    // C[q = i*16+l16][d = j*16+quad*4+r]; plain float4 partial stores.
    float* pslice = part + (size_t)z * NQ * DIM;
#pragma unroll
    for (int i = 0; i < 8; ++i) {
        int qrow = q0 + wm * 128 + i * 16 + l16;
#pragma unroll
        for (int j = 0; j < 4; ++j) {
            int dcol = d0 + wn * 64 + j * 16 + quad * 4;
            float4 v;
            v.x = acc[i][j][0]; v.y = acc[i][j][1];
            v.z = acc[i][j][2]; v.w = acc[i][j][3];
            *(float4*)&pslice[(size_t)qrow * DIM + dcol] = v;
        }
    }
}

// ---------------------------------------------------------------------------
// reduce: out[q][d] = (sum_z part[z][q][d]) / lsum[q]
// ---------------------------------------------------------------------------
__global__ void reduce_out(const float* __restrict__ part,
                           const float* __restrict__ lsum,
                           float* __restrict__ out) {
    size_t idx = ((size_t)blockIdx.x * 256 + threadIdx.x) * 4;
    int q = (int)(idx >> 10);
    float inv = 1.0f / lsum[q];
    const size_t S = (size_t)NQ * DIM;
    float4 s0 = *(const float4*)(part + idx);
    float4 s1 = *(const float4*)(part + S + idx);
    float4 s2 = *(const float4*)(part + 2 * S + idx);
    float4 s3 = *(const float4*)(part + 3 * S + idx);
    float4 o;
    o.x = (s0.x + s1.x + s2.x + s3.x) * inv;
    o.y = (s0.y + s1.y + s2.y + s3.y) * inv;
    o.z = (s0.z + s1.z + s2.z + s3.z) * inv;
    o.w = (s0.w + s1.w + s2.w + s3.w) * inv;
    *(float4*)(out + idx) = o;
}

// ---------------------------------------------------------------------------
// GEMM 2 tier-2 (exact R10): atomics into pre-zeroed out.
// ---------------------------------------------------------------------------
__global__ void ctx_gemm(const unsigned short* __restrict__ P,
                         const unsigned short* __restrict__ Kt,
                         const float* __restrict__ lsum,
                         float* __restrict__ out) {
    __shared__ __align__(16) unsigned short As[128 * 32];
    __shared__ __align__(16) unsigned short Bs[128 * 32];
    int id = blockIdx.x;
    int r8 = id & 7;
    int t  = id >> 3;
    int x  = t & 7;
    int g  = ((t >> 3) << 3) | r8;
    int y  = g & 31;
    int z  = g >> 5;
    int q0 = y * 128;
    int d0 = x * 128;
    int kbase = z * (NK / 4);

    int tid = threadIdx.x;
    int wave = tid >> 6, lane = tid & 63;
    int wm = wave >> 1, wn = wave & 1;
    int quad = lane >> 4, l16 = lane & 15;

    int srow   = wave * 32 + (lane >> 2);
    int schunk = (((lane & 3) ^ ((lane >> 3) & 3))) * 8;
    const unsigned short* gA0 = P + (size_t)(q0 + srow) * NK + kbase + schunk;
    const unsigned short* gA1 = gA0 + (size_t)16 * NK;
    const unsigned short* gB0 = Kt + (size_t)(d0 + srow) * NK + kbase + schunk;
    const unsigned short* gB1 = gB0 + (size_t)16 * NK;
    unsigned short* lA0 = As + wave * 32 * 32;
    unsigned short* lA1 = lA0 + 16 * 32;
    unsigned short* lB0 = Bs + wave * 32 * 32;
    unsigned short* lB1 = lB0 + 16 * 32;

    int rcol = (quad ^ ((l16 >> 1) & 3)) * 8;

    floatx4 acc[4][4];
#pragma unroll
    for (int i = 0; i < 4; ++i)
#pragma unroll
        for (int j = 0; j < 4; ++j) acc[i][j] = (floatx4)(0.0f);

    for (int kb = 0; kb < (NK / 4) / 32; ++kb) {
        int k0 = kb * 32;
        __syncthreads();
        gload_lds16(gA0 + k0, lA0);
        gload_lds16(gA1 + k0, lA1);
        gload_lds16(gB0 + k0, lB0);
        gload_lds16(gB1 + k0, lB1);
        __syncthreads();
        short8 a[4], b[4];
#pragma unroll
        for (int i = 0; i < 4; ++i)
            a[i] = *(const short8*)&As[(wm * 64 + i * 16 + l16) * 32 + rcol];
#pragma unroll
        for (int j = 0; j < 4; ++j)
            b[j] = *(const short8*)&Bs[(wn * 64 + j * 16 + l16) * 32 + rcol];
#pragma unroll
        for (int i = 0; i < 4; ++i)
#pragma unroll
            for (int j = 0; j < 4; ++j)
                acc[i][j] = __builtin_amdgcn_mfma_f32_16x16x32_bf16(a[i], b[j], acc[i][j], 0, 0, 0);
    }

#pragma unroll
    for (int i = 0; i < 4; ++i) {
        float invl[4];
#pragma unroll
        for (int r = 0; r < 4; ++r)
            invl[r] = 1.0f / lsum[q0 + wm * 64 + i * 16 + quad * 4 + r];
#pragma unroll
        for (int j = 0; j < 4; ++j) {
#pragma unroll
            for (int r = 0; r < 4; ++r) {
                int qrow = q0 + wm * 64 + i * 16 + quad * 4 + r;
                int dcol = d0 + wn * 64 + j * 16 + l16;
                atomicAdd(&out[(size_t)qrow * DIM + dcol], acc[i][j][r] * invl[r]);
            }
        }
    }
}

// ---------------------------------------------------------------------------
// Path D fallback (ws too small) — correct but slow.
// ---------------------------------------------------------------------------
__global__ void fused_fallback(const float* __restrict__ Q,
                               const float* __restrict__ K,
                               float* __restrict__ out) {
    int wave = threadIdx.x >> 6, lane = threadIdx.x & 63;
    int q0 = blockIdx.x * 16 + wave * 4;
    float qv[4][16], acc[4][16], iqn[4], ls[4];
#pragma unroll
    for (int r = 0; r < 4; ++r) {
        float s = 0.f;
#pragma unroll
        for (int c = 0; c < 4; ++c) {
            float4 f = *(const float4*)(Q + (size_t)(q0 + r) * DIM + c * 256 + lane * 4);
            qv[r][c * 4 + 0] = f.x; qv[r][c * 4 + 1] = f.y;
            qv[r][c * 4 + 2] = f.z; qv[r][c * 4 + 3] = f.w;
            s += f.x * f.x + f.y * f.y + f.z * f.z + f.w * f.w;
        }
#pragma unroll
        for (int off = 32; off > 0; off >>= 1) s += __shfl_xor(s, off);
        iqn[r] = 1.0f / sqrtf(s);
        ls[r] = 0.f;
#pragma unroll
        for (int t = 0; t < 16; ++t) acc[r][t] = 0.f;
    }
    for (int k = 0; k < NK; ++k) {
        const float* kr = K + (size_t)k * DIM;
        float kv[16], ss = 0.f;
#pragma unroll
        for (int c = 0; c < 4; ++c) {
            float4 f = *(const float4*)(kr + c * 256 + lane * 4);
            kv[c * 4 + 0] = f.x; kv[c * 4 + 1] = f.y;
            kv[c * 4 + 2] = f.z; kv[c * 4 + 3] = f.w;
            ss += f.x * f.x + f.y * f.y + f.z * f.z + f.w * f.w;
        }
        float d0 = 0.f, d1 = 0.f, d2 = 0.f, d3 = 0.f;
#pragma unroll
        for (int t = 0; t < 16; ++t) {
            d0 += qv[0][t] * kv[t]; d1 += qv[1][t] * kv[t];
            d2 += qv[2][t] * kv[t]; d3 += qv[3][t] * kv[t];
        }
#pragma unroll
        for (int off = 32; off > 0; off >>= 1) {
            ss += __shfl_xor(ss, off);
            d0 += __shfl_xor(d0, off); d1 += __shfl_xor(d1, off);
            d2 += __shfl_xor(d2, off); d3 += __shfl_xor(d3, off);
        }
        float ikn = 1.0f / sqrtf(ss);
        float p0 = __expf(d0 * iqn[0] * ikn), p1 = __expf(d1 * iqn[1] * ikn);
        float p2 = __expf(d2 * iqn[2] * ikn), p3 = __expf(d3 * iqn[3] * ikn);
        ls[0] += p0; ls[1] += p1; ls[2] += p2; ls[3] += p3;
#pragma unroll
        for (int t = 0; t < 16; ++t) {
            acc[0][t] += p0 * kv[t]; acc[1][t] += p1 * kv[t];
            acc[2][t] += p2 * kv[t]; acc[3][t] += p3 * kv[t];
        }
    }
#pragma unroll
    for (int r = 0; r < 4; ++r) {
        float inv = 1.0f / ls[r];
#pragma unroll
        for (int c = 0; c < 4; ++c) {
            float4 o;
            o.x = acc[r][c * 4 + 0] * inv; o.y = acc[r][c * 4 + 1] * inv;
            o.z = acc[r][c * 4 + 2] * inv; o.w = acc[r][c * 4 + 3] * inv;
            *(float4*)(out + (size_t)(q0 + r) * DIM + c * 256 + lane * 4) = o;
        }
    }
}

// ---------------------------------------------------------------------------
// launch — tiers:
//  T1 (ws>=152M+64K): Kt[0,16M) overlap Qb/Kb, P[24,88M), part[88,152M),
//                     scalars @152M; ctx_gemm_st + reduce_out.
//  T2 (ws>=88M+64K):  exact R10 (atomics).
//  else: fallback.
// ---------------------------------------------------------------------------
extern "C" void kernel_launch(void* const* d_in, const int* in_sizes, int n_in,
                              void* d_out, int out_size, void* d_ws, size_t ws_size,
                              hipStream_t stream) {
    const float* Q = (const float*)d_in[0];
    const float* K = (const float*)d_in[1];
    float* out = (float*)d_out;
    char* ws = (char*)d_ws;

    const size_t REQ_T1 = ((size_t)152u << 20) + 65536;
    const size_t REQ_T2 = ((size_t)88u << 20) + 65536;

    if (ws_size >= REQ_T1) {
        unsigned short* Kt = (unsigned short*)(ws);
        unsigned short* Qb = (unsigned short*)(ws);
        unsigned short* Kb = (unsigned short*)(ws + (size_t)(8u << 20));
        unsigned short* P  = (unsigned short*)(ws + (size_t)(24u << 20));
        float* part   = (float*)(ws + (size_t)(88u << 20));
        float* inv_qn = (float*)(ws + (size_t)(152u << 20));
        float* inv_kn = (float*)(ws + (size_t)(152u << 20) + 16384);
        float* lsum   = (float*)(ws + (size_t)(152u << 20) + 49152);

        prep_q_zero<<<NQ / 4, 256, 0, stream>>>(Q, Qb, inv_qn, lsum, nullptr);
        prep_norm_cvt<<<NK / 4, 256, 0, stream>>>(K, Kb, inv_kn);
        score_gemm<<<512, 512, 0, stream>>>(Qb, Kb, inv_qn, inv_kn, P, lsum);
        transpose_cvt<<<dim3(NK / 64, DIM / 64), 256, 0, stream>>>(K, Kt);
        ctx_gemm_st<<<256, 512, 0, stream>>>(P, Kt, part);
        reduce_out<<<NQ * DIM / 1024, 256, 0, stream>>>(part, lsum, out);
    } else if (ws_size >= REQ_T2) {
        unsigned short* Kt = (unsigned short*)(ws);
        unsigned short* Qb = (unsigned short*)(ws);
        unsigned short* Kb = (unsigned short*)(ws + (size_t)(8u << 20));
        unsigned short* P  = (unsigned short*)(ws + (size_t)(24u << 20));
        float* inv_qn = (float*)(ws + (size_t)(88u << 20));
        float* inv_kn = (float*)(ws + (size_t)(88u << 20) + 16384);
        float* lsum   = (float*)(ws + (size_t)(88u << 20) + 49152);

        prep_q_zero<<<NQ / 4, 256, 0, stream>>>(Q, Qb, inv_qn, lsum, out);
        prep_norm_cvt<<<NK / 4, 256, 0, stream>>>(K, Kb, inv_kn);
        score_gemm<<<512, 512, 0, stream>>>(Qb, Kb, inv_qn, inv_kn, P, lsum);
        transpose_cvt<<<dim3(NK / 64, DIM / 64), 256, 0, stream>>>(K, Kt);
        ctx_gemm<<<1024, 256, 0, stream>>>(P, Kt, lsum, out);
    } else {
        fused_fallback<<<NQ / 16, 256, 0, stream>>>(Q, K, out);
    }
}